// Round 12
// baseline (14.644 us; speedup 1.0000x reference)
//
#include <hip/hip_runtime.h>

// out[b,o] = min_i max(x[b,i], w[i,o])  — exact hard min via bucket-sorted
// early-exit scan (absmax 0.0 since R4).
//
// R12: cut gather TRAFFIC (R4-R11 flatness => bound is L1/L2 gather work,
// ~150MB for straight-64). Per-LANE stop ~25 entries; per-wave ballot needs
// ~60. So: straight-line 32 entries, then per-lane PREDICATED 8-entry chunks
// (done lanes exec-masked off -> their fetches never reach TA/L1/L2), ballot
// exit per chunk. ~47% traffic cut. Phase A = R11's cheap 64-bin sort.
// Predication is monotone-correct: lane skips iff A <= th(chunk); th is
// nondecreasing, all unseen values >= th, so skipped lanes are final.

#define B_DIM 512
#define I_DIM 512
#define O_DIM 1024
#define NBUCK 64

#define RL(v_, l_) ((unsigned)__builtin_amdgcn_readlane((int)(v_), (l_)))
#define RFL(v_) ((unsigned)__builtin_amdgcn_readfirstlane((int)(v_)))

__global__ __launch_bounds__(256, 8) void SmoothSTEMinMax_fused(
    const float* __restrict__ x,     // [B, I]
    const float* __restrict__ w,     // [I, O]
    float* __restrict__ out) {       // [B, O]
  __shared__ unsigned int hist[NBUCK];
  __shared__ uint2 sdat[I_DIM];      // {w-row byte offset, x valbits}, bucket-ordered

  const int t = threadIdx.x;
  const int b = blockIdx.x;          // row
  const int lane = t & 63;

  // ---- Phase A: 64-bin counting sort (4 barriers, 1-wave prefix scan) ----
  const float xv0 = x[b * I_DIM + t];
  const float xv1 = x[b * I_DIM + 256 + t];
  int b0 = (int)(xv0 * 64.0f); b0 = b0 > 63 ? 63 : (b0 < 0 ? 0 : b0);
  int b1 = (int)(xv1 * 64.0f); b1 = b1 > 63 ? 63 : (b1 < 0 ? 0 : b1);

  if (t < NBUCK) hist[t] = 0;
  __syncthreads();
  atomicAdd(&hist[b0], 1u);
  atomicAdd(&hist[b1], 1u);
  __syncthreads();
  if (t < NBUCK) {                   // wave 0 only: shfl inclusive scan
    const unsigned cnt = hist[t];
    unsigned v = cnt;
#pragma unroll
    for (int d = 1; d < 64; d <<= 1) {
      const unsigned n = __shfl_up(v, d, 64);
      if (lane >= d) v += n;
    }
    hist[t] = v - cnt;               // exclusive base -> bucket cursor
  }
  __syncthreads();
  {
    const unsigned p0 = atomicAdd(&hist[b0], 1u);
    sdat[p0] = make_uint2((unsigned)t * (unsigned)(O_DIM * 4), __float_as_uint(xv0));
    const unsigned p1 = atomicAdd(&hist[b1], 1u);
    sdat[p1] = make_uint2((unsigned)(t + 256) * (unsigned)(O_DIM * 4),
                          __float_as_uint(xv1));
  }
  __syncthreads();

  // ---- Phase B: register-broadcast scan, predicated tail ----
  const unsigned o4 = (unsigned)(blockIdx.y * 256 + t) * 4u;  // output byte offset
  const char* wb = reinterpret_cast<const char*>(w);
  float A = 3.402823466e+38f;

  // entries 0..127: lane l holds entries 2l (q.x=off,q.y=val), 2l+1 (q.z,q.w)
  const uint4 q = *reinterpret_cast<const uint4*>(&sdat[2 * lane]);

  // straight-line first 32 entries: zero checks, full global-load ILP
#pragma unroll
  for (int c = 0; c < 4; ++c) {
    float wv[8], xv[8];
#pragma unroll
    for (int e = 0; e < 8; ++e) {
      const int g = c * 8 + e;
      const unsigned off = RL((g & 1) ? q.z : q.x, g >> 1);
      const unsigned xb  = RL((g & 1) ? q.w : q.y, g >> 1);
      xv[e] = __uint_as_float(xb);
      wv[e] = *reinterpret_cast<const float*>(wb + (off + o4));
    }
#pragma unroll
    for (int e = 0; e < 8; ++e) A = fminf(A, fmaxf(xv[e], wv[e]));
  }

  int k = 32;
  // predicated adaptive region: entries 32..127.  Lanes with A <= th skip the
  // loads entirely (exec-masked) -> no L1/L2 traffic for finished outputs.
#pragma unroll
  for (int c = 4; c < 16; ++c) {
    const float nx = __uint_as_float(RL(q.y, 4 * c));        // value of entry 8c
    const float th = (float)(int)(nx * 64.0f) * 0.015625f;   // bucket lower bound
    const bool need = (A > th);
    if (!__any(need)) break;                                 // exact early exit
    if (need) {                                              // per-lane predication
#pragma unroll
      for (int e = 0; e < 8; ++e) {
        const int g = c * 8 + e;
        const unsigned off = RL((g & 1) ? q.z : q.x, g >> 1);
        const unsigned xb  = RL((g & 1) ? q.w : q.y, g >> 1);
        const float wvv = *reinterpret_cast<const float*>(wb + (off + o4));
        A = fminf(A, fmaxf(__uint_as_float(xb), wvv));
      }
    }
    k += 8;
  }

  // LDS fallback: entries 128..511 (probability ~0; correctness only)
  if (k >= 128) {
    while (k < I_DIM) {
      const float nx = __uint_as_float(RFL(sdat[k].y));
      const float th = (float)(int)(nx * 64.0f) * 0.015625f;
      const bool need = (A > th);
      if (!__any(need)) break;
      if (need) {
#pragma unroll
        for (int u = 0; u < 8; ++u) {
          const unsigned off = RFL(sdat[k + u].x);
          const unsigned xb  = RFL(sdat[k + u].y);
          const float wvv = *reinterpret_cast<const float*>(wb + (off + o4));
          A = fminf(A, fmaxf(__uint_as_float(xb), wvv));
        }
      }
      k += 8;
    }
  }

  out[b * O_DIM + blockIdx.y * 256 + t] = A;
}

extern "C" void kernel_launch(void* const* d_in, const int* in_sizes, int n_in,
                              void* d_out, int out_size, void* d_ws, size_t ws_size,
                              hipStream_t stream) {
  const float* x = (const float*)d_in[0];   // [512, 512]
  const float* w = (const float*)d_in[1];   // [512, 1024]
  float* out = (float*)d_out;               // [512, 1024]

  dim3 grid(B_DIM, O_DIM / 256);            // 512 x 4 = 2048 blocks, 4 waves each
  SmoothSTEMinMax_fused<<<grid, 256, 0, stream>>>(x, w, out);
}

// Round 13
// 14.175 us; speedup vs baseline: 1.0331x; 1.0331x over previous
//
#include <hip/hip_runtime.h>

// out[b,o] = min_i max(x[b,i], w[i,o])  — exact hard min via bucket-sorted
// early-exit scan (absmax 0.0 since R4).
//
// R13: raise per-wave MEMORY-LEVEL PARALLELISM. R4-R12 all ran under
// launch_bounds(...,8) => 32-VGPR cap => compiler kept only ~8 gathers in
// flight (VGPR_Count=20 in R9) => ~9 serialized latency-batches per pass.
// Now: launch_bounds(256,4) (64-VGPR cap, still 32 waves/CU at <=64 VGPRs)
// + explicit 32-deep pipeline: issue entries 0..31 into a 32-reg circular
// buffer, then rolling {consume 8, issue 8}. Latency exposure ~9 -> ~2-3
// batches. Phase A = R11 64-bin sort; exit bound = next entry's bucket
// lower bound (exact).

#define B_DIM 512
#define I_DIM 512
#define O_DIM 1024
#define NBUCK 64

#define RL(v_, l_) ((unsigned)__builtin_amdgcn_readlane((int)(v_), (l_)))
#define RFL(v_) ((unsigned)__builtin_amdgcn_readfirstlane((int)(v_)))

// issue chunk c (entries 8c..8c+7): gather loads only, no consumption
#define ISSUE(c_)                                                       \
  _Pragma("unroll") for (int e = 0; e < 8; ++e) {                       \
    const int g = (c_) * 8 + e;                                         \
    const unsigned off = RL((g & 1) ? q.z : q.x, g >> 1);               \
    wv[((c_) & 3) * 8 + e] =                                            \
        *reinterpret_cast<const float*>(wb + (off + o4));               \
  }

// consume chunk c: x values re-broadcast from q (compile-time readlane)
#define CONSUME(c_)                                                     \
  _Pragma("unroll") for (int e = 0; e < 8; ++e) {                       \
    const int g = (c_) * 8 + e;                                         \
    const unsigned xb = RL((g & 1) ? q.w : q.y, g >> 1);                \
    A = fminf(A, fmaxf(__uint_as_float(xb), wv[((c_) & 3) * 8 + e]));   \
  }

__global__ __launch_bounds__(256, 4) void SmoothSTEMinMax_fused(
    const float* __restrict__ x,     // [B, I]
    const float* __restrict__ w,     // [I, O]
    float* __restrict__ out) {       // [B, O]
  __shared__ unsigned int hist[NBUCK];
  __shared__ uint2 sdat[I_DIM];      // {w-row byte offset, x valbits}, bucket-ordered

  const int t = threadIdx.x;
  const int b = blockIdx.x;          // row
  const int lane = t & 63;

  // ---- Phase A: 64-bin counting sort (4 barriers, 1-wave prefix scan) ----
  const float xv0 = x[b * I_DIM + t];
  const float xv1 = x[b * I_DIM + 256 + t];
  int b0 = (int)(xv0 * 64.0f); b0 = b0 > 63 ? 63 : (b0 < 0 ? 0 : b0);
  int b1 = (int)(xv1 * 64.0f); b1 = b1 > 63 ? 63 : (b1 < 0 ? 0 : b1);

  if (t < NBUCK) hist[t] = 0;
  __syncthreads();
  atomicAdd(&hist[b0], 1u);
  atomicAdd(&hist[b1], 1u);
  __syncthreads();
  if (t < NBUCK) {                   // wave 0 only: shfl inclusive scan
    const unsigned cnt = hist[t];
    unsigned v = cnt;
#pragma unroll
    for (int d = 1; d < 64; d <<= 1) {
      const unsigned n = __shfl_up(v, d, 64);
      if (lane >= d) v += n;
    }
    hist[t] = v - cnt;               // exclusive base -> bucket cursor
  }
  __syncthreads();
  {
    const unsigned p0 = atomicAdd(&hist[b0], 1u);
    sdat[p0] = make_uint2((unsigned)t * (unsigned)(O_DIM * 4), __float_as_uint(xv0));
    const unsigned p1 = atomicAdd(&hist[b1], 1u);
    sdat[p1] = make_uint2((unsigned)(t + 256) * (unsigned)(O_DIM * 4),
                          __float_as_uint(xv1));
  }
  __syncthreads();

  // ---- Phase B: 32-deep pipelined gather scan, 1 output/lane ----
  const unsigned o4 = (unsigned)(blockIdx.y * 256 + t) * 4u;  // output byte offset
  const char* wb = reinterpret_cast<const char*>(w);
  float A = 3.402823466e+38f;

  // entries 0..127: lane l holds entries 2l (q.x=off,q.y=val), 2l+1 (q.z,q.w)
  const uint4 q = *reinterpret_cast<const uint4*>(&sdat[2 * lane]);

  float wv[32];                      // 32 gathers in flight (circular, 4 chunks)

  // fill the pipe: entries 0..31 (32 loads outstanding)
  ISSUE(0) ISSUE(1) ISSUE(2) ISSUE(3)
  // rolling: consume 8, issue 8 (keeps ~32 in flight)
  CONSUME(0) ISSUE(4)
  CONSUME(1) ISSUE(5)
  CONSUME(2) ISSUE(6)
  CONSUME(3) ISSUE(7)
  // drain
  CONSUME(4) CONSUME(5) CONSUME(6) CONSUME(7)

  int k = 64;
  // register-resident adaptive tail: entries 64..127, exit check per 8
#pragma unroll
  for (int c = 8; c < 16; ++c) {
    const float nx = __uint_as_float(RL(q.y, 4 * c));        // value of entry 8c
    const float th = (float)(int)(nx * 64.0f) * 0.015625f;   // bucket lower bound
    if (!__any(A > th)) break;                               // exact early exit
#pragma unroll
    for (int e = 0; e < 8; ++e) {
      const int g = c * 8 + e;
      const unsigned off = RL((g & 1) ? q.z : q.x, g >> 1);
      const unsigned xb  = RL((g & 1) ? q.w : q.y, g >> 1);
      const float wvv = *reinterpret_cast<const float*>(wb + (off + o4));
      A = fminf(A, fmaxf(__uint_as_float(xb), wvv));
    }
    k += 8;
  }

  // LDS fallback: entries 128..511 (probability ~0; correctness only)
  if (k >= 128) {
    while (k < I_DIM) {
      const float nx = __uint_as_float(RFL(sdat[k].y));
      const float th = (float)(int)(nx * 64.0f) * 0.015625f;
      if (!__any(A > th)) break;
#pragma unroll
      for (int u = 0; u < 8; ++u) {
        const unsigned off = RFL(sdat[k + u].x);
        const unsigned xb  = RFL(sdat[k + u].y);
        const float wvv = *reinterpret_cast<const float*>(wb + (off + o4));
        A = fminf(A, fmaxf(__uint_as_float(xb), wvv));
      }
      k += 8;
    }
  }

  out[b * O_DIM + blockIdx.y * 256 + t] = A;
}

extern "C" void kernel_launch(void* const* d_in, const int* in_sizes, int n_in,
                              void* d_out, int out_size, void* d_ws, size_t ws_size,
                              hipStream_t stream) {
  const float* x = (const float*)d_in[0];   // [512, 512]
  const float* w = (const float*)d_in[1];   // [512, 1024]
  float* out = (float*)d_out;               // [512, 1024]

  dim3 grid(B_DIM, O_DIM / 256);            // 512 x 4 = 2048 blocks, 4 waves each
  SmoothSTEMinMax_fused<<<grid, 256, 0, stream>>>(x, w, out);
}

// Round 14
// 14.142 us; speedup vs baseline: 1.0355x; 1.0023x over previous
//
#include <hip/hip_runtime.h>

// out[b,o] = min_i max(x[b,i], w[i,o])  — exact hard min via bucket-sorted
// early-exit scan (absmax 0.0 since R4).
//
// R14 = R11 + XCD-aware block remap (T1). Diagnosis: R9 algebra shows a
// warm repeat pass costs ~6.5us but every timed replay pays ~13.6 — per-XCD
// L2 (4MB) can't retain the ~3.3MB all-XCDs-touch-all-of-w working set
// between replays. Remap: bid%8 = XCD (HW round-robin), slice = bid&3,
// row = bid>>2  =>  each XCD serves ONE 256-col w slice (512KB) + half the
// x rows (512KB) => ~1.3MB/XCD, L2-resident across replays.
//
// Phase A: 64-bin counting sort (4 barriers, 1-wave shfl prefix scan).
// Phase B: entries 0..127 in one uint4/lane, compile-time v_readlane
// broadcast; 64 straight-line; per-8 checked tail (exit bound = next
// entry's bucket lower bound — exact); ~never-taken LDS fallback.

#define B_DIM 512
#define I_DIM 512
#define O_DIM 1024
#define NBUCK 64

#define RL(v_, l_) ((unsigned)__builtin_amdgcn_readlane((int)(v_), (l_)))
#define RFL(v_) ((unsigned)__builtin_amdgcn_readfirstlane((int)(v_)))

__global__ __launch_bounds__(256, 8) void SmoothSTEMinMax_fused(
    const float* __restrict__ x,     // [B, I]
    const float* __restrict__ w,     // [I, O]
    float* __restrict__ out) {       // [B, O]
  __shared__ unsigned int hist[NBUCK];
  __shared__ uint2 sdat[I_DIM];      // {w-row byte offset, x valbits}, bucket-ordered

  const int t = threadIdx.x;
  const int bid = blockIdx.x;
  const int sl = bid & 3;            // o-slice: constant per XCD (bid%8 -> XCD)
  const int b = bid >> 2;            // row
  const int lane = t & 63;

  // ---- Phase A: 64-bin counting sort (4 barriers, 1-wave prefix scan) ----
  const float xv0 = x[b * I_DIM + t];
  const float xv1 = x[b * I_DIM + 256 + t];
  int b0 = (int)(xv0 * 64.0f); b0 = b0 > 63 ? 63 : (b0 < 0 ? 0 : b0);
  int b1 = (int)(xv1 * 64.0f); b1 = b1 > 63 ? 63 : (b1 < 0 ? 0 : b1);

  if (t < NBUCK) hist[t] = 0;
  __syncthreads();
  atomicAdd(&hist[b0], 1u);
  atomicAdd(&hist[b1], 1u);
  __syncthreads();
  if (t < NBUCK) {                   // wave 0 only: shfl inclusive scan
    const unsigned cnt = hist[t];
    unsigned v = cnt;
#pragma unroll
    for (int d = 1; d < 64; d <<= 1) {
      const unsigned n = __shfl_up(v, d, 64);
      if (lane >= d) v += n;
    }
    hist[t] = v - cnt;               // exclusive base -> bucket cursor
  }
  __syncthreads();
  {
    const unsigned p0 = atomicAdd(&hist[b0], 1u);
    sdat[p0] = make_uint2((unsigned)t * (unsigned)(O_DIM * 4), __float_as_uint(xv0));
    const unsigned p1 = atomicAdd(&hist[b1], 1u);
    sdat[p1] = make_uint2((unsigned)(t + 256) * (unsigned)(O_DIM * 4),
                          __float_as_uint(xv1));
  }
  __syncthreads();

  // ---- Phase B: register-broadcast early-exit scan ----
  const unsigned o4 = (unsigned)(sl * 256 + t) * 4u;  // output byte offset
  const char* wb = reinterpret_cast<const char*>(w);
  float A = 3.402823466e+38f;

  // entries 0..127: lane l holds entries 2l (q.x=off,q.y=val), 2l+1 (q.z,q.w)
  const uint4 q = *reinterpret_cast<const uint4*>(&sdat[2 * lane]);

  // straight-line first 64 entries: zero checks, full global-load ILP
#pragma unroll
  for (int c = 0; c < 8; ++c) {
    float wv[8], xv[8];
#pragma unroll
    for (int e = 0; e < 8; ++e) {
      const int g = c * 8 + e;
      const unsigned off = RL((g & 1) ? q.z : q.x, g >> 1);
      const unsigned xb  = RL((g & 1) ? q.w : q.y, g >> 1);
      xv[e] = __uint_as_float(xb);
      wv[e] = *reinterpret_cast<const float*>(wb + (off + o4));
    }
#pragma unroll
    for (int e = 0; e < 8; ++e) A = fminf(A, fmaxf(xv[e], wv[e]));
  }

  int k = 64;
  // register-resident adaptive tail: entries 64..127, exit check per 8
#pragma unroll
  for (int c = 8; c < 16; ++c) {
    const float nx = __uint_as_float(RL(q.y, 4 * c));        // value of entry 8c
    const float th = (float)(int)(nx * 64.0f) * 0.015625f;   // bucket lower bound
    if (!__any(A > th)) break;                               // exact early exit
#pragma unroll
    for (int e = 0; e < 8; ++e) {
      const int g = c * 8 + e;
      const unsigned off = RL((g & 1) ? q.z : q.x, g >> 1);
      const unsigned xb  = RL((g & 1) ? q.w : q.y, g >> 1);
      const float wvv = *reinterpret_cast<const float*>(wb + (off + o4));
      A = fminf(A, fmaxf(__uint_as_float(xb), wvv));
    }
    k += 8;
  }

  // LDS fallback: entries 128..511 (probability ~0; correctness only)
  if (k >= 128) {
    while (k < I_DIM) {
      const float nx = __uint_as_float(RFL(sdat[k].y));
      const float th = (float)(int)(nx * 64.0f) * 0.015625f;
      if (!__any(A > th)) break;
#pragma unroll
      for (int u = 0; u < 8; ++u) {
        const unsigned off = RFL(sdat[k + u].x);
        const unsigned xb  = RFL(sdat[k + u].y);
        const float wvv = *reinterpret_cast<const float*>(wb + (off + o4));
        A = fminf(A, fmaxf(__uint_as_float(xb), wvv));
      }
      k += 8;
    }
  }

  out[b * O_DIM + sl * 256 + t] = A;
}

extern "C" void kernel_launch(void* const* d_in, const int* in_sizes, int n_in,
                              void* d_out, int out_size, void* d_ws, size_t ws_size,
                              hipStream_t stream) {
  const float* x = (const float*)d_in[0];   // [512, 512]
  const float* w = (const float*)d_in[1];   // [512, 1024]
  float* out = (float*)d_out;               // [512, 1024]

  // 1D grid: bid%8 = XCD; slice = bid&3 (one w-col slice per XCD), row = bid>>2
  SmoothSTEMinMax_fused<<<B_DIM * 4, 256, 0, stream>>>(x, w, out);
}